// Round 2
// baseline (418.209 us; speedup 1.0000x reference)
//
#include <hip/hip_runtime.h>

#define N_NODES 10000
#define N_EDGES 320000
#define N_CAND  100000
#define HID     256
#define N_MP    3
#define N_ATYPE 100

static __device__ __forceinline__ float relu_f(float x) { return x > 0.f ? x : 0.f; }

// ---------------------------------------------------------------------------
// GEMM core: C[M x 256] tile (mb, nb) = act(A[Mx256] @ B[256x64 slice] + bias)
// BM=64, BN=64, BK=32; 128 threads; per-thread 8 rows x 4 cols.
// ---------------------------------------------------------------------------
static __device__ __forceinline__ void gemm_core(
    const float* __restrict__ A, const float* __restrict__ B,
    const float* __restrict__ bias, float* __restrict__ C,
    int M, int mb, int nb, int doRelu)
{
    __shared__ float As[32][68];   // [k][m] transposed; stride 68 floats (16B-aligned rows)
    __shared__ float Bs[32][68];   // [k][n]

    int tid = threadIdx.x;
    int tx = tid & 15;             // 16 col groups * 4 cols
    int ty = tid >> 4;             // 8 row groups * 8 rows

    float acc[8][4] = {};

    for (int k0 = 0; k0 < 256; k0 += 32) {
        // A tile: 64 rows x 32 k  (coalesced float4 along K, transposed store)
        #pragma unroll
        for (int p = 0; p < 4; ++p) {
            int flat = p * 128 + tid;      // 0..511
            int row  = flat >> 3;          // 0..63
            int kc   = flat & 7;           // 0..7 (4 floats each)
            float4 av = make_float4(0.f, 0.f, 0.f, 0.f);
            if (mb + row < M)
                av = *(const float4*)(A + (size_t)(mb + row) * 256 + k0 + kc * 4);
            As[kc * 4 + 0][row] = av.x;
            As[kc * 4 + 1][row] = av.y;
            As[kc * 4 + 2][row] = av.z;
            As[kc * 4 + 3][row] = av.w;
        }
        // B tile: 32 k x 64 cols (row-major float4 copy)
        #pragma unroll
        for (int p = 0; p < 4; ++p) {
            int flat = p * 128 + tid;
            int row  = flat >> 4;          // 0..31
            int c    = flat & 15;          // 0..15
            *(float4*)(&Bs[row][c * 4]) =
                *(const float4*)(B + (size_t)(k0 + row) * 256 + nb + c * 4);
        }
        __syncthreads();

        #pragma unroll
        for (int k = 0; k < 32; ++k) {
            float4 a0 = *(const float4*)(&As[k][ty * 8]);
            float4 a1 = *(const float4*)(&As[k][ty * 8 + 4]);
            float4 b4 = *(const float4*)(&Bs[k][tx * 4]);
            float a[8] = {a0.x, a0.y, a0.z, a0.w, a1.x, a1.y, a1.z, a1.w};
            float b[4] = {b4.x, b4.y, b4.z, b4.w};
            #pragma unroll
            for (int i = 0; i < 8; ++i)
                #pragma unroll
                for (int j = 0; j < 4; ++j)
                    acc[i][j] = fmaf(a[i], b[j], acc[i][j]);
        }
        __syncthreads();
    }

    float bvv[4] = {0.f, 0.f, 0.f, 0.f};
    if (bias) {
        float4 bv = *(const float4*)(bias + nb + tx * 4);
        bvv[0] = bv.x; bvv[1] = bv.y; bvv[2] = bv.z; bvv[3] = bv.w;
    }
    #pragma unroll
    for (int i = 0; i < 8; ++i) {
        int row = mb + ty * 8 + i;
        if (row >= M) continue;
        float r[4];
        #pragma unroll
        for (int j = 0; j < 4; ++j) {
            r[j] = acc[i][j] + bvv[j];
            if (doRelu) r[j] = relu_f(r[j]);
        }
        *(float4*)(C + (size_t)row * 256 + nb + tx * 4) =
            make_float4(r[0], r[1], r[2], r[3]);
    }
}

__global__ __launch_bounds__(128) void k_gemm(
    const float* __restrict__ A, const float* __restrict__ B,
    const float* __restrict__ bias, float* __restrict__ C,
    int M, int doRelu)
{
    gemm_core(A, B, bias, C, M, blockIdx.x * 64, blockIdx.y * 64, doRelu);
}

// Merged P/Q projection: P = A @ W1[0:256,:], Q = A @ W1[256:512,:] (no bias/relu)
__global__ __launch_bounds__(128) void k_gemm_pq(
    const float* __restrict__ A, const float* __restrict__ W1,
    float* __restrict__ P, float* __restrict__ Q, int M)
{
    int half = blockIdx.y >> 2;           // 0 -> P (top rows of W1), 1 -> Q
    const float* B = W1 + (size_t)half * 256 * 256;
    float* C = half ? Q : P;
    gemm_core(A, B, nullptr, C, M, blockIdx.x * 64, (blockIdx.y & 3) * 64, 0);
}

// ---------------------------------------------------------------------------
__global__ void k_hist(const int* __restrict__ ei,
                       int* __restrict__ dout, int* __restrict__ din)
{
    int e = blockIdx.x * blockDim.x + threadIdx.x;
    if (e >= N_EDGES) return;
    atomicAdd(&dout[ei[e]], 1);
    atomicAdd(&din[ei[N_EDGES + e]], 1);
}

__global__ void k_norm(const int* __restrict__ dout, const int* __restrict__ din,
                       float* __restrict__ ns, float* __restrict__ nd)
{
    int i = blockIdx.x * blockDim.x + threadIdx.x;
    if (i >= N_NODES) return;
    int o = dout[i], in = din[i];
    ns[i] = (o  > 0) ? (1.0f / sqrtf((float)o))  : 0.f;
    nd[i] = (in > 0) ? (1.0f / sqrtf((float)in)) : 0.f;
}

__global__ __launch_bounds__(256) void k_h0(const int* __restrict__ types,
                                            const float* __restrict__ E0,
                                            float* __restrict__ h)
{
    int node = blockIdx.x * 4 + (threadIdx.x >> 6);
    int lane = threadIdx.x & 63;
    if (node >= N_NODES) return;
    int t = types[node];
    ((float4*)h)[node * 64 + lane] = ((const float4*)E0)[t * 64 + lane];
}

__global__ __launch_bounds__(256) void k_scan(const int* __restrict__ deg,
                                              int* __restrict__ off, int n)
{
    __shared__ int part[256];
    int t = threadIdx.x;
    int chunk = (n + 255) / 256;
    int base = t * chunk;
    int s = 0;
    for (int i = 0; i < chunk; ++i) {
        int idx = base + i;
        if (idx < n) s += deg[idx];
    }
    part[t] = s;
    __syncthreads();
    for (int d = 1; d < 256; d <<= 1) {
        int v = (t >= d) ? part[t - d] : 0;
        __syncthreads();
        part[t] += v;
        __syncthreads();
    }
    int run = (t == 0) ? 0 : part[t - 1];
    if (t == 0) off[0] = 0;
    for (int i = 0; i < chunk; ++i) {
        int idx = base + i;
        if (idx < n) { run += deg[idx]; off[idx + 1] = run; }
    }
}

__global__ void k_fill(const int* __restrict__ ei, const int* __restrict__ off,
                       int* __restrict__ cur, int* __restrict__ csr)
{
    int e = blockIdx.x * blockDim.x + threadIdx.x;
    if (e >= N_EDGES) return;
    int d = ei[N_EDGES + e];
    int p = off[d] + atomicAdd(&cur[d], 1);
    csr[p] = ei[e];
}

// agg[n][:] = norm_dst[n] * sum_{e in in(n)} h[src(e)][:] * norm_src[src(e)]
// One wave per node; unroll-by-4 for memory-level parallelism.
__global__ __launch_bounds__(256) void k_agg(
    const float* __restrict__ h, const float* __restrict__ ns,
    const float* __restrict__ nd, const int* __restrict__ off,
    const int* __restrict__ csr, float* __restrict__ out)
{
    int node = blockIdx.x * 4 + (threadIdx.x >> 6);
    int lane = threadIdx.x & 63;
    if (node >= N_NODES) return;
    int s0 = off[node], s1 = off[node + 1];
    const float4* h4 = (const float4*)h;

    float4 acc0 = make_float4(0.f, 0.f, 0.f, 0.f);
    float4 acc1 = make_float4(0.f, 0.f, 0.f, 0.f);

    int e = s0;
    for (; e + 4 <= s1; e += 4) {
        int i0 = csr[e], i1 = csr[e + 1], i2 = csr[e + 2], i3 = csr[e + 3];
        float w0 = ns[i0], w1 = ns[i1], w2 = ns[i2], w3 = ns[i3];
        float4 v0 = h4[(size_t)i0 * 64 + lane];
        float4 v1 = h4[(size_t)i1 * 64 + lane];
        float4 v2 = h4[(size_t)i2 * 64 + lane];
        float4 v3 = h4[(size_t)i3 * 64 + lane];
        acc0.x = fmaf(v0.x, w0, acc0.x); acc0.y = fmaf(v0.y, w0, acc0.y);
        acc0.z = fmaf(v0.z, w0, acc0.z); acc0.w = fmaf(v0.w, w0, acc0.w);
        acc1.x = fmaf(v1.x, w1, acc1.x); acc1.y = fmaf(v1.y, w1, acc1.y);
        acc1.z = fmaf(v1.z, w1, acc1.z); acc1.w = fmaf(v1.w, w1, acc1.w);
        acc0.x = fmaf(v2.x, w2, acc0.x); acc0.y = fmaf(v2.y, w2, acc0.y);
        acc0.z = fmaf(v2.z, w2, acc0.z); acc0.w = fmaf(v2.w, w2, acc0.w);
        acc1.x = fmaf(v3.x, w3, acc1.x); acc1.y = fmaf(v3.y, w3, acc1.y);
        acc1.z = fmaf(v3.z, w3, acc1.z); acc1.w = fmaf(v3.w, w3, acc1.w);
    }
    for (; e < s1; ++e) {
        int s = csr[e];
        float w = ns[s];
        float4 hv = h4[(size_t)s * 64 + lane];
        acc0.x = fmaf(hv.x, w, acc0.x); acc0.y = fmaf(hv.y, w, acc0.y);
        acc0.z = fmaf(hv.z, w, acc0.z); acc0.w = fmaf(hv.w, w, acc0.w);
    }
    float d = nd[node];
    float4 r;
    r.x = (acc0.x + acc1.x) * d;
    r.y = (acc0.y + acc1.y) * d;
    r.z = (acc0.z + acc1.z) * d;
    r.w = (acc0.w + acc1.w) * d;
    ((float4*)out)[node * 64 + lane] = r;
}

// scores[c] = relu(P[u]+Q[v]+b1) . W2 + b2   (one wave per candidate)
__global__ __launch_bounds__(256) void k_score(
    const int* __restrict__ cand, const float* __restrict__ P,
    const float* __restrict__ Q, const float* __restrict__ b1,
    const float* __restrict__ W2, const float* __restrict__ b2,
    float* __restrict__ out)
{
    int c = blockIdx.x * 4 + (threadIdx.x >> 6);
    int lane = threadIdx.x & 63;
    if (c >= N_CAND) return;
    int u = cand[2 * c];
    int v = cand[2 * c + 1];
    float4 p = ((const float4*)P)[(size_t)u * 64 + lane];
    float4 q = ((const float4*)Q)[(size_t)v * 64 + lane];
    float4 b = ((const float4*)b1)[lane];
    float4 w = ((const float4*)W2)[lane];
    float hx = relu_f(p.x + q.x + b.x);
    float hy = relu_f(p.y + q.y + b.y);
    float hz = relu_f(p.z + q.z + b.z);
    float hw = relu_f(p.w + q.w + b.w);
    float d = hx * w.x + hy * w.y + hz * w.z + hw * w.w;
    #pragma unroll
    for (int o = 32; o > 0; o >>= 1)
        d += __shfl_xor(d, o, 64);
    if (lane == 0) out[c] = d + b2[0];
}

// ---------------------------------------------------------------------------
extern "C" void kernel_launch(void* const* d_in, const int* in_sizes, int n_in,
                              void* d_out, int out_size, void* d_ws, size_t ws_size,
                              hipStream_t stream)
{
    const int*   atom_types = (const int*)d_in[0];
    const int*   edge_index = (const int*)d_in[2];
    const int*   candidates = (const int*)d_in[3];
    const float* atom_embed = (const float*)d_in[4];
    const float* atom_W     = (const float*)d_in[5];
    const float* atom_b     = (const float*)d_in[6];
    const float* conv_W     = (const float*)d_in[10];
    const float* conv_b     = (const float*)d_in[11];
    const float* s_W1       = (const float*)d_in[12];
    const float* s_b1       = (const float*)d_in[13];
    const float* s_W2       = (const float*)d_in[14];
    const float* s_b2       = (const float*)d_in[15];
    float* out = (float*)d_out;

    char* w = (char*)d_ws;
    size_t o = 0;
    auto alloc = [&](size_t bytes) {
        void* p = w + o;
        o += (bytes + 255) & ~(size_t)255;
        return p;
    };
    float* h0  = (float*)alloc((size_t)N_NODES * HID * 4);
    float* h1  = (float*)alloc((size_t)N_NODES * HID * 4);
    float* agg = (float*)alloc((size_t)N_NODES * HID * 4);
    float* E0  = (float*)alloc((size_t)N_ATYPE * HID * 4);
    int*   ints = (int*)alloc((size_t)3 * N_NODES * 4);   // dego | degi | cursor
    float* ns  = (float*)alloc((size_t)N_NODES * 4);
    float* nd  = (float*)alloc((size_t)N_NODES * 4);
    int*   off = (int*)alloc((size_t)(N_NODES + 1) * 4);
    int*   csr = (int*)alloc((size_t)N_EDGES * 4);
    int* dego = ints;
    int* degi = ints + N_NODES;
    int* cur  = ints + 2 * N_NODES;

    hipMemsetAsync(ints, 0, (size_t)3 * N_NODES * 4, stream);

    // E0 = atom_embed @ atom_W + atom_b   (100 x 256)
    k_gemm<<<dim3(2, 4), 128, 0, stream>>>(atom_embed, atom_W, atom_b, E0, N_ATYPE, 0);

    k_hist<<<(N_EDGES + 255) / 256, 256, 0, stream>>>(edge_index, dego, degi);
    k_norm<<<(N_NODES + 255) / 256, 256, 0, stream>>>(dego, degi, ns, nd);
    k_h0<<<N_NODES / 4, 256, 0, stream>>>(atom_types, E0, h0);
    k_scan<<<1, 256, 0, stream>>>(degi, off, N_NODES);
    k_fill<<<(N_EDGES + 255) / 256, 256, 0, stream>>>(edge_index, off, cur, csr);

    const float* hc = h0;
    float* hn = h1;
    const int GX = (N_NODES + 63) / 64;
    for (int i = 0; i < N_MP; ++i) {
        k_agg<<<N_NODES / 4, 256, 0, stream>>>(hc, ns, nd, off, csr, agg);
        k_gemm<<<dim3(GX, 4), 128, 0, stream>>>(
            agg, conv_W + (size_t)i * HID * HID, conv_b + (size_t)i * HID, hn, N_NODES, 1);
        float* t = (float*)hc; hc = hn; hn = t;
    }
    // P = h @ W1_top, Q = h @ W1_bot — merged single launch for full occupancy
    float* P = agg;
    float* Q = hn;
    k_gemm_pq<<<dim3(GX, 8), 128, 0, stream>>>(hc, s_W1, P, Q, N_NODES);

    k_score<<<N_CAND / 4, 256, 0, stream>>>(candidates, P, Q, s_b1, s_W2, s_b2, out);
}